// Round 8
// baseline (121.572 us; speedup 1.0000x reference)
//
#include <hip/hip_runtime.h>
#include <math.h>

// FedTGPClientLoss: fused CE (log-softmax gather) + prototype-MSE.
// B=16384, C=1000, D=512.
// R11 = R10 (best, 119.9us) + exact-shape specialization of the fast path:
//   - C4 in (192,256] and D4==128 -> logits chunks 0-2 always in-range
//     (drop 8 cndmasks), features/protos chunk 1 always in-range (drop
//     clamp+select), only chunk 3 of logits needs -inf padding.
//   - safe_exp's fmin NaN-guard dropped on the fast path: every lane's m is
//     finite there (chunks 0-2 are real values), so dm<=0 always and
//     exp(-inf)=0 handles the padded chunk-3 elements naturally.
// Structure unchanged: one row/wave, 4 waves/block, launch_bounds(256,8),
// scalar-path uniform loads (labels/label-logit via readfirstlane SGPR),
// per-block double2 partials, 1-block finalize.
// Fixed floor: two 256MiB harness poison fills ~83us of the ~120 total.

#ifndef INFINITY
#define INFINITY __builtin_inff()
#endif

__device__ __forceinline__ float safe_exp(float dm) {
    // exp(min(dm,0)): guards the (-inf)-(-inf)=NaN case on padded lanes in
    // the generic fallback path.
    return __expf(fminf(dm, 0.0f));
}

__global__ __launch_bounds__(256, 8) void fedtgp_rows(
    const float* __restrict__ logits,
    const int*   __restrict__ labels,
    const float* __restrict__ features,
    const float* __restrict__ protos,
    double2* __restrict__ part,         // per-block (ce_sum, pl_sum)
    int B, int C, int D)
{
    const int tid  = threadIdx.x;
    const int lane = tid & 63;
    const int wv   = tid >> 6;
    const int row  = blockIdx.x * 4 + wv;

    __shared__ double sc[4], sp[4];

    float ce = 0.f, pl = 0.f;
    const bool valid = (row < B);

    if (valid) {
        // row is wave-uniform; pin into SGPR so label + label-logit gathers
        // take the scalar-load path and vector loads get SGPR bases.
        const int srow = __builtin_amdgcn_readfirstlane(row);
        const int lab  = labels[srow];
        const int C4 = C >> 2;
        const int D4 = D >> 2;
        const float* lrow = logits + (size_t)srow * C;

        if (C4 > 192 && C4 <= 256 && D4 == 128 &&
            (C & 3) == 0 && (D & 3) == 0) {
            // ---- exact-shape fast path (C=1000 -> C4=250, D=512) ----
            const float4* l4 = (const float4*)lrow;
            const float4* f4 = (const float4*)(features + (size_t)srow * D);
            const float4* p4 = (const float4*)(protos   + (size_t)lab * D);

            // chunks 0-2 always in-range: lane+128 <= 191 < C4.
            const int i3 = min(lane + 192, C4 - 1);

            // 8 vector loads + scalar label-logit, all independent.
            float4 v0 = l4[lane];
            float4 v1 = l4[lane + 64];
            float4 v2 = l4[lane + 128];
            float4 v3 = l4[i3];
            float4 f0 = f4[lane];
            float4 f1 = f4[lane + 64];          // D4==128: always in-range
            float4 p0 = p4[lane];
            float4 p1 = p4[lane + 64];
            const float ll = lrow[lab];          // SGPR addr -> s_load

            const bool b3 = (lane + 192 < C4);
            const float NI = -INFINITY;
            v3.x = b3 ? v3.x : NI; v3.y = b3 ? v3.y : NI;
            v3.z = b3 ? v3.z : NI; v3.w = b3 ? v3.w : NI;

            // per-lane max: finite for every lane (chunks 0-2 are real).
            float m = fmaxf(fmaxf(fmaxf(v0.x, v0.y), fmaxf(v0.z, v0.w)),
                            fmaxf(fmaxf(v1.x, v1.y), fmaxf(v1.z, v1.w)));
            m = fmaxf(m, fmaxf(fmaxf(v2.x, v2.y), fmaxf(v2.z, v2.w)));
            m = fmaxf(m, fmaxf(fmaxf(v3.x, v3.y), fmaxf(v3.z, v3.w)));

            // no fmin guard needed: dm <= 0 always, exp(-inf)=0 for padding.
            float s = __expf(v0.x - m) + __expf(v0.y - m)
                    + __expf(v0.z - m) + __expf(v0.w - m);
            s += __expf(v1.x - m) + __expf(v1.y - m)
               + __expf(v1.z - m) + __expf(v1.w - m);
            s += __expf(v2.x - m) + __expf(v2.y - m)
               + __expf(v2.z - m) + __expf(v2.w - m);
            s += __expf(v3.x - m) + __expf(v3.y - m)
               + __expf(v3.z - m) + __expf(v3.w - m);

            float dx = f0.x - p0.x, dy = f0.y - p0.y;
            float dz = f0.z - p0.z, dw = f0.w - p0.w;
            float q = dx * dx + dy * dy + dz * dz + dw * dw;
            dx = f1.x - p1.x; dy = f1.y - p1.y;
            dz = f1.z - p1.z; dw = f1.w - p1.w;
            q += dx * dx + dy * dy + dz * dz + dw * dw;

            // max butterfly -> one rescale exp -> (s,q) sum butterfly.
            float M = m;
            #pragma unroll
            for (int off = 32; off > 0; off >>= 1)
                M = fmaxf(M, __shfl_xor(M, off, 64));
            s *= __expf(m - M);                 // m,M finite; dm <= 0
            #pragma unroll
            for (int off = 32; off > 0; off >>= 1) {
                s += __shfl_xor(s, off, 64);
                q += __shfl_xor(q, off, 64);
            }

            ce = (M + __logf(s)) - ll;
            pl = q / (float)D;
        } else {
            // ---- generic fallback (correctness only; not the bench shape) --
            float m = -INFINITY, s = 0.f, q = 0.f;
            for (int c = lane; c < C; c += 64) {
                const float x  = lrow[c];
                const float cm = fmaxf(m, x);
                s = s * safe_exp(m - cm) + safe_exp(x - cm);
                m = cm;
            }
            for (int d = lane; d < D; d += 64) {
                const float df = features[(size_t)srow * D + d]
                               - protos[(size_t)lab * D + d];
                q += df * df;
            }
            const float ll = lrow[lab];
            #pragma unroll
            for (int off = 32; off > 0; off >>= 1) {
                const float om = __shfl_xor(m, off, 64);
                const float os = __shfl_xor(s, off, 64);
                q += __shfl_xor(q, off, 64);
                const float nm = fmaxf(m, om);
                s = s * safe_exp(m - nm) + os * safe_exp(om - nm);
                m = nm;
            }
            ce = (m + __logf(s)) - ll;
            pl = q / (float)D;
        }
    }

    if (lane == 0) {
        sc[wv] = valid ? (double)ce : 0.0;
        sp[wv] = valid ? (double)pl : 0.0;
    }
    __syncthreads();
    if (tid == 0)
        part[blockIdx.x] = make_double2(sc[0] + sc[1] + sc[2] + sc[3],
                                        sp[0] + sp[1] + sp[2] + sp[3]);
}

__global__ __launch_bounds__(1024) void fedtgp_finalize(
    const double2* __restrict__ part,
    float* __restrict__ out,
    int npart, double invB)
{
    const int tid  = threadIdx.x;
    const int lane = tid & 63;
    const int wv   = tid >> 6;
    __shared__ double rc[16];
    __shared__ double rp[16];

    double c = 0.0, p = 0.0;
    for (int i = tid; i < npart; i += 1024) {
        const double2 v = part[i];
        c += v.x;
        p += v.y;
    }
    #pragma unroll
    for (int off = 32; off > 0; off >>= 1) {
        c += __shfl_xor(c, off, 64);
        p += __shfl_xor(p, off, 64);
    }
    if (lane == 0) { rc[wv] = c; rp[wv] = p; }
    __syncthreads();

    if (tid == 0) {
        double cs = 0.0, ps = 0.0;
        #pragma unroll
        for (int k = 0; k < 16; ++k) { cs += rc[k]; ps += rp[k]; }
        float ce = (float)(cs * invB);
        float pl = (float)(ps * invB);
        if (!isfinite(ce)) ce = 0.0f;          // ce_loss = where(isfinite, ce, 0)
        float tot = ce + pl;                   // LAMDA = 1.0
        if (!isfinite(tot)) tot = ce;          // total = where(isfinite, total, ce)
        out[0] = tot;
        out[1] = ce;
        out[2] = pl;
    }
}

extern "C" void kernel_launch(void* const* d_in, const int* in_sizes, int n_in,
                              void* d_out, int out_size, void* d_ws, size_t ws_size,
                              hipStream_t stream)
{
    const float* logits   = (const float*)d_in[0];
    const int*   labels   = (const int*)  d_in[1];
    const float* features = (const float*)d_in[2];
    const float* protos   = (const float*)d_in[3];
    float* out = (float*)d_out;

    const int B = in_sizes[1];              // 16384
    const int C = in_sizes[0] / B;          // 1000
    const int D = in_sizes[2] / B;          // 512

    int nb = (B + 3) / 4;                   // one row per wave, 4 waves/block
    const size_t need_per_block = sizeof(double2);
    if ((size_t)nb * need_per_block > ws_size) {
        nb = (int)(ws_size / need_per_block); // degenerate-guard; never hit here
        if (nb < 1) nb = 1;
    }

    double2* part = (double2*)d_ws;         // nb * 16 B = 64 KB << ws_size

    fedtgp_rows<<<nb, 256, 0, stream>>>(logits, labels, features, protos,
                                        part, B, C, D);
    fedtgp_finalize<<<1, 1024, 0, stream>>>(part, out, nb, 1.0 / (double)B);
}